// Round 7
// baseline (265.197 us; speedup 1.0000x reference)
//
#include <hip/hip_runtime.h>
#include <hip/hip_bf16.h>
#include <cstdint>
#include <cstddef>

#define DM   256
#define DI   512
#define DS   16
#define LSEQ 4096
#define BATCH 2
#define BLROWS (BATCH * LSEQ)   /* 8192 */
#define NCH  128                /* chunks per sequence */
#define CLEN 32                 /* steps per chunk */
#define XCP  520                /* padded LDS row stride (u16) */

/* fused_a LDS layout (bytes) */
#define OFF_INW 0               /* 128*256*2 = 65536 */
#define OFF_XC  0               /* overlay after in_proj: 32*520*2 = 33280 */
#define OFF_Z   65536           /* 48*264*2 = 25344 */
#define OFF_XD  65536           /* overlay: 32*68*4 = 8704 */
#define OFF_XX  90880           /* 35*520*2 = 36400 */
#define SMEM_SZ 127280

typedef __bf16 bf16x8 __attribute__((ext_vector_type(8)));
typedef float  f32x4  __attribute__((ext_vector_type(4)));
typedef unsigned short u16;
typedef u16 u16x8 __attribute__((ext_vector_type(8)));
typedef u16 u16x4 __attribute__((ext_vector_type(4)));

__device__ __forceinline__ u16 f2bfu(float f) {
    union { float f; unsigned u; } c; c.f = f;
    unsigned u = c.u;
    return (u16)((u + 0x7fffu + ((u >> 16) & 1u)) >> 16);
}
__device__ __forceinline__ float bfu2f(u16 u) {
    union { unsigned u; float f; } c; c.u = ((unsigned)u) << 16; return c.f;
}
__device__ __forceinline__ float siluf(float v) {
    return v * (1.0f / (1.0f + __expf(-v)));
}
__device__ __forceinline__ void gload_lds16(const void* g, void* l) {
    __builtin_amdgcn_global_load_lds(
        (const __attribute__((address_space(1))) unsigned int*)g,
        (__attribute__((address_space(3))) unsigned int*)l, 16, 0, 0);
}

/* ---------------- merged startup casts ---------------- */
#define N_INW  (2*1024*256)
#define N_OUTW (2*256*512)
#define N_XPW  (2*64*512)
#define N_Z    (BLROWS*DM)
__global__ __launch_bounds__(256) void cast_all_k(
    const float* __restrict__ in_w, const float* __restrict__ out_w,
    const float* __restrict__ xp_w, const float* __restrict__ z,
    u16* __restrict__ inw_bf, u16* __restrict__ outw_bf,
    u16* __restrict__ xpw_bf, u16* __restrict__ z_bf) {
    int i = blockIdx.x * 256 + threadIdx.x;
    if (i < N_INW) {
        inw_bf[i] = f2bfu(in_w[i]);
    } else if (i < N_INW + N_OUTW) {
        int j = i - N_INW;
        outw_bf[j] = f2bfu(out_w[j]);
    } else if (i < N_INW + N_OUTW + N_XPW) {
        int j = i - (N_INW + N_OUTW);
        int k = j & 511, o = (j >> 9) & 63, l = j >> 15;
        xpw_bf[j] = f2bfu((o < 48) ? xp_w[(l * 48 + o) * 512 + k] : 0.0f);
    } else {
        int j = i - (N_INW + N_OUTW + N_XPW);
        z_bf[j] = f2bfu(z[j]);
    }
}

/* ---------------- fused A: in_proj MFMA -> conv+silu -> x_proj -> dt -> scan -- */
/* grid (NCH, BATCH), 512 threads (8 waves). One block = one chunk, all 512 ch.  */
__global__ __launch_bounds__(512) void fused_a_k(
    const u16* __restrict__ zin, const u16* __restrict__ inw,
    const float* __restrict__ cw, const float* __restrict__ cb,
    const __bf16* __restrict__ xpw,
    const float* __restrict__ dtw, const float* __restrict__ dtb,
    const float* __restrict__ Alog,
    u16* __restrict__ xcb, u16* __restrict__ dtob, u16* __restrict__ gateb,
    float* __restrict__ BCg, u16* __restrict__ Pb, u16* __restrict__ Sb) {
    __shared__ __align__(16) char smem[SMEM_SZ];
    u16*  inw_s = (u16*)(smem + OFF_INW);
    u16*  z_s   = (u16*)(smem + OFF_Z);
    u16*  xx_s  = (u16*)(smem + OFF_XX);
    u16*  xc_s  = (u16*)(smem + OFF_XC);
    float* xd_s = (float*)(smem + OFF_XD);
    int tid = threadIdx.x;
    int c = blockIdx.x, b = blockIdx.y;
    int bl0 = b * LSEQ + c * CLEN;
    int wave = tid >> 6, lane = tid & 63;
    int row = lane & 15, q = lane >> 4;
    int d = tid;

    /* stage z slab: LDS rows 0..47 = t -3..44; rows>=35 zero; c==0 rows<3 zero */
    for (int idx = tid; idx < 48 * 32; idx += 512) {
        int r = idx >> 5, c8 = idx & 31;
        u16x8 v = {0,0,0,0,0,0,0,0};
        if (r < 35 && (c > 0 || r >= 3))
            v = *(const u16x8*)(zin + (size_t)(bl0 - 3 + r) * DM + c8 * 8);
        *(u16x8*)(z_s + r * 264 + c8 * 8) = v;
    }
    __syncthreads();

    /* in_proj: 8 col-groups of 128; stage inw swizzled, mfma 48x128 per group */
    for (int g = 0; g < 8; ++g) {
        {   /* stage 64 KB: wave w covers rows w*16..w*16+15, 8 instrs x 2 rows */
            int pos = lane & 31, roff = lane >> 5;
            #pragma unroll
            for (int i = 0; i < 8; ++i) {
                int r_abs = wave * 16 + i * 2 + roff;
                int chunk = (pos - r_abs) & 31;   /* rotate chunk pos by row */
                gload_lds16(inw + (size_t)(g * 128 + r_abs) * 256 + chunk * 8,
                            inw_s + (wave * 16 + i * 2) * 256);
            }
        }
        __syncthreads();
        f32x4 acc[3] = {};
        #pragma unroll
        for (int kb = 0; kb < 8; ++kb) {
            int cidx = kb * 4 + q;
            int r_abs = wave * 16 + row;
            int pos = (cidx + r_abs) & 31;
            bf16x8 bb = *(const bf16x8*)(inw_s + r_abs * 256 + pos * 8);
            #pragma unroll
            for (int mt = 0; mt < 3; ++mt) {
                bf16x8 a = *(const bf16x8*)(z_s + (mt*16 + row) * 264 + kb*32 + q*8);
                acc[mt] = __builtin_amdgcn_mfma_f32_16x16x32_bf16(a, bb, acc[mt], 0, 0, 0);
            }
        }
        __syncthreads();
        /* write out: cols g*128 + wave*16 + row (C-layout: row = q*4+r) */
        int col = g * 128 + wave * 16 + row;
        #pragma unroll
        for (int mt = 0; mt < 3; ++mt)
            #pragma unroll
            for (int r = 0; r < 4; ++r) {
                int grow = mt * 16 + q * 4 + r;
                if (g < 4) {
                    if (grow < 35) xx_s[grow * XCP + col] = f2bfu(acc[mt][r]);
                } else {
                    int t = grow - 3;
                    if (t >= 0 && t < CLEN)
                        gateb[(size_t)(bl0 + t) * DI + (col - 512)] = f2bfu(acc[mt][r]);
                }
            }
    }
    __syncthreads();

    /* conv + silu: thread = channel; x(t') = xx_s[(t'+3)*XCP + d] */
    {
        float w0 = cw[d*4], w1 = cw[d*4+1], w2 = cw[d*4+2], w3 = cw[d*4+3];
        float bias = cb[d];
        float xm3 = bfu2f(xx_s[0*XCP + d]);
        float xm2 = bfu2f(xx_s[1*XCP + d]);
        float xm1 = bfu2f(xx_s[2*XCP + d]);
        #pragma unroll 4
        for (int t = 0; t < CLEN; ++t) {
            float xcur = bfu2f(xx_s[(t + 3) * XCP + d]);
            float v = siluf(fmaf(w0, xm3, fmaf(w1, xm2, fmaf(w2, xm1, fmaf(w3, xcur, bias)))));
            u16 vb = f2bfu(v);
            xc_s[t * XCP + d] = vb;                       /* overlays inw_s (dead) */
            xcb[(size_t)(bl0 + t) * DI + d] = vb;
            xm3 = xm2; xm2 = xm1; xm1 = xcur;
        }
    }
    __syncthreads();

    /* x_proj: xd[32,64] = xc_s[32,512] @ xpw[64,512]^T (8 waves: mt 2 x nt 4) */
    {
        int mt = wave & 1, nt = wave >> 1;
        f32x4 acc = {0.f, 0.f, 0.f, 0.f};
        #pragma unroll
        for (int kb = 0; kb < 16; ++kb) {
            bf16x8 a = *(const bf16x8*)&xc_s[(mt*16 + row) * XCP + kb*32 + q*8];
            bf16x8 bb = *(const bf16x8*)(xpw + (size_t)(nt*16 + row) * 512 + kb*32 + q*8);
            acc = __builtin_amdgcn_mfma_f32_16x16x32_bf16(a, bb, acc, 0, 0, 0);
        }
        #pragma unroll
        for (int r = 0; r < 4; ++r)
            xd_s[(mt*16 + q*4 + r) * 68 + nt*16 + row] = acc[r];   /* overlays z_s */
    }
    __syncthreads();

    /* store compact B,C (cols 16..47) for fused_c */
    for (int i = tid; i < CLEN * 32; i += 512) {
        int t = i >> 5, cc = i & 31;
        BCg[((size_t)(b*NCH + c) * CLEN + t) * 32 + cc] = xd_s[t*68 + 16 + cc];
    }

    /* dt = softplus(xd[:, :16] @ dtw^T + dtb); chunk scan -> P,S (bf16) */
    {
        float dtwr[16];
        const f32x4* w4 = (const f32x4*)(dtw + (size_t)d * 16);
        #pragma unroll
        for (int g = 0; g < 4; ++g) { f32x4 v = w4[g];
            dtwr[g*4] = v[0]; dtwr[g*4+1] = v[1]; dtwr[g*4+2] = v[2]; dtwr[g*4+3] = v[3]; }
        float dtbv = dtb[d];
        float Ac[16];
        const f32x4* a4 = (const f32x4*)(Alog + (size_t)d * 16);
        #pragma unroll
        for (int g = 0; g < 4; ++g) { f32x4 v = a4[g];
            #pragma unroll
            for (int j = 0; j < 4; ++j) Ac[g*4+j] = -__expf(v[j]); }
        bool fastp = true;
        #pragma unroll
        for (int n = 1; n < 16; ++n)
            fastp = fastp && (fabsf(Ac[n] - (float)(n+1) * Ac[0]) <= 1e-4f * fabsf(Ac[n]));
        float p[16], s[16];
        #pragma unroll
        for (int n = 0; n < 16; ++n) { p[n] = 1.0f; s[n] = 0.0f; }
        for (int t = 0; t < CLEN; ++t) {
            float acc = dtbv;
            #pragma unroll
            for (int r = 0; r < 16; ++r) acc = fmaf(xd_s[t*68 + r], dtwr[r], acc);
            float dtv = (acc > 20.0f) ? acc : logf(1.0f + __expf(acc));
            dtob[(size_t)(bl0 + t) * DI + d] = f2bfu(dtv);
            float xv = bfu2f(xc_s[t * XCP + d]);
            float dx = dtv * xv;
            float an[16];
            if (fastp) {
                float a0 = __expf(dtv * Ac[0]);
                an[0] = a0;
                #pragma unroll
                for (int n = 1; n < 16; ++n) an[n] = an[n-1] * a0;
            } else {
                #pragma unroll
                for (int n = 0; n < 16; ++n) an[n] = __expf(dtv * Ac[n]);
            }
            #pragma unroll
            for (int n = 0; n < 16; ++n) {
                s[n] = fmaf(an[n], s[n], xd_s[t*68 + 16 + n] * dx);
                p[n] *= an[n];
            }
        }
        size_t base = ((size_t)(b*NCH + c) * DI + d) * 16;
        u16x8 pv0, pv1, sv0, sv1;
        #pragma unroll
        for (int n = 0; n < 8; ++n) {
            pv0[n] = f2bfu(p[n]);   pv1[n] = f2bfu(p[8+n]);
            sv0[n] = f2bfu(s[n]);   sv1[n] = f2bfu(s[8+n]);
        }
        *(u16x8*)(Pb + base)     = pv0;  *(u16x8*)(Pb + base + 8) = pv1;
        *(u16x8*)(Sb + base)     = sv0;  *(u16x8*)(Sb + base + 8) = sv1;
    }
}

/* ---------------- scanB: stitch chunk entry states (bf16 P,S -> f32 H) -------- */
__global__ __launch_bounds__(256) void scanB_k(
    const u16* __restrict__ Pb, const u16* __restrict__ Sb,
    float* __restrict__ H) {
    int i = blockIdx.x * 256 + threadIdx.x;   /* BATCH*DI*DS/4 = 4096 */
    int b = i >> 11, j4 = i & 2047;
    f32x4 h = {0.f, 0.f, 0.f, 0.f};
    for (int c = 0; c < NCH; ++c) {
        size_t i4 = (size_t)(b*NCH + c) * 2048 + j4;
        u16x4 pv = ((const u16x4*)Pb)[i4];
        u16x4 sv = ((const u16x4*)Sb)[i4];
        ((f32x4*)H)[i4] = h;
        #pragma unroll
        for (int j = 0; j < 4; ++j) h[j] = fmaf(bfu2f(pv[j]), h[j], bfu2f(sv[j]));
    }
}

/* ---------------- fused C: scan replay -> y slab (LDS) -> out_proj MFMA ------- */
__global__ __launch_bounds__(512) void fused_c_k(
    const u16* __restrict__ xcb, const u16* __restrict__ dtob,
    const float* __restrict__ BCg, const float* __restrict__ H,
    const float* __restrict__ Alog, const float* __restrict__ Dp,
    const u16* __restrict__ gateb, const __bf16* __restrict__ outw,
    u16* __restrict__ Ob, float* __restrict__ Of) {
    __shared__ u16 y_s[CLEN * XCP];        /* 33.3 KB */
    __shared__ float BCs[CLEN * 32];       /* 4 KB */
    int tid = threadIdx.x;
    int c = blockIdx.x, b = blockIdx.y;
    int bl0 = b * LSEQ + c * CLEN;
    int d = tid;

    for (int i = tid; i < CLEN * 32; i += 512)
        BCs[i] = BCg[(size_t)(b*NCH + c) * (CLEN*32) + i];

    float Ac[16], h[16];
    {
        const f32x4* a4 = (const f32x4*)(Alog + (size_t)d * 16);
        const f32x4* h4 = (const f32x4*)(H + ((size_t)(b*NCH + c) * DI + d) * 16);
        #pragma unroll
        for (int g = 0; g < 4; ++g) {
            f32x4 av = a4[g]; f32x4 hv = h4[g];
            #pragma unroll
            for (int j = 0; j < 4; ++j) { Ac[g*4+j] = -__expf(av[j]); h[g*4+j] = hv[j]; }
        }
    }
    bool fastp = true;
    #pragma unroll
    for (int n = 1; n < 16; ++n)
        fastp = fastp && (fabsf(Ac[n] - (float)(n+1) * Ac[0]) <= 1e-4f * fabsf(Ac[n]));
    float Dv = Dp[d];
    __syncthreads();

    #pragma unroll 4
    for (int t = 0; t < CLEN; ++t) {
        float dtv = bfu2f(dtob[(size_t)(bl0 + t) * DI + d]);
        float xv  = bfu2f(xcb[(size_t)(bl0 + t) * DI + d]);
        float gv  = bfu2f(gateb[(size_t)(bl0 + t) * DI + d]);
        float dx = dtv * xv;
        float an[16];
        if (fastp) {
            float a0 = __expf(dtv * Ac[0]);
            an[0] = a0;
            #pragma unroll
            for (int n = 1; n < 16; ++n) an[n] = an[n-1] * a0;
        } else {
            #pragma unroll
            for (int n = 0; n < 16; ++n) an[n] = __expf(dtv * Ac[n]);
        }
        float y = 0.f;
        #pragma unroll
        for (int n = 0; n < 16; ++n) {
            h[n] = fmaf(an[n], h[n], BCs[t*32 + n] * dx);
            y = fmaf(h[n], BCs[t*32 + 16 + n], y);
        }
        float yv = fmaf(xv, Dv, y) * siluf(gv);
        y_s[t * XCP + d] = f2bfu(yv);
    }
    __syncthreads();

    /* out_proj: O[32,256] = y_s[32,512] @ outw[256,512]^T; 8 waves: mt 2 x ng 4 */
    {
        int wave = tid >> 6, lane = tid & 63;
        int row = lane & 15, q = lane >> 4;
        int mt = wave & 1, ng = wave >> 1;
        f32x4 acc[4] = {};
        #pragma unroll
        for (int kb = 0; kb < 16; ++kb) {
            bf16x8 a = *(const bf16x8*)&y_s[(mt*16 + row) * XCP + kb*32 + q*8];
            #pragma unroll
            for (int ni = 0; ni < 4; ++ni) {
                bf16x8 bb = *(const bf16x8*)(outw +
                    (size_t)(ng*64 + ni*16 + row) * 512 + kb*32 + q*8);
                acc[ni] = __builtin_amdgcn_mfma_f32_16x16x32_bf16(a, bb, acc[ni], 0, 0, 0);
            }
        }
        #pragma unroll
        for (int r = 0; r < 4; ++r) {
            size_t gr = (size_t)(bl0 + mt*16 + q*4 + r) * DM;
            #pragma unroll
            for (int ni = 0; ni < 4; ++ni) {
                int gc = ng*64 + ni*16 + row;
                if (Ob) Ob[gr + gc] = f2bfu(acc[ni][r]);
                else    Of[gr + gc] = acc[ni][r];
            }
        }
    }
}

/* ================================================================== */
extern "C" void kernel_launch(void* const* d_in, const int* in_sizes, int n_in,
                              void* d_out, int out_size, void* d_ws, size_t ws_size,
                              hipStream_t stream) {
    (void)in_sizes; (void)n_in; (void)out_size; (void)ws_size;
    const float* z_in   = (const float*)d_in[0];
    const float* in_w   = (const float*)d_in[1];
    const float* conv_w = (const float*)d_in[2];
    const float* conv_b = (const float*)d_in[3];
    const float* xp_w   = (const float*)d_in[4];
    const float* dt_w   = (const float*)d_in[5];
    const float* dt_b   = (const float*)d_in[6];
    const float* A_log  = (const float*)d_in[7];
    const float* D_par  = (const float*)d_in[8];
    const float* out_w  = (const float*)d_in[9];
    float* outp = (float*)d_out;

    char* p = (char*)d_ws;
    auto alloc = [&](size_t bytes) { char* r = p; p += (bytes + 255) & ~(size_t)255; return r; };
    u16* z_bf    = (u16*)alloc((size_t)BLROWS*DM*2);
    u16* z2_bf   = (u16*)alloc((size_t)BLROWS*DM*2);
    u16* xc_bf   = (u16*)alloc((size_t)BLROWS*DI*2);
    u16* dt_bf   = (u16*)alloc((size_t)BLROWS*DI*2);
    u16* gate_bf = (u16*)alloc((size_t)BLROWS*DI*2);
    u16* inw_bf  = (u16*)alloc((size_t)2*1024*256*2);
    u16* outw_bf = (u16*)alloc((size_t)2*256*512*2);
    u16* xpw_bf  = (u16*)alloc((size_t)2*64*512*2);
    float* BCg   = (float*)alloc((size_t)BATCH*NCH*CLEN*32*4);
    u16* Pbuf    = (u16*)alloc((size_t)BATCH*NCH*DI*DS*2);
    u16* Sbuf    = (u16*)alloc((size_t)BATCH*NCH*DI*DS*2);
    float* Hbuf  = (float*)alloc((size_t)BATCH*NCH*DI*DS*4);

    cast_all_k<<<(N_INW + N_OUTW + N_XPW + N_Z)/256, 256, 0, stream>>>(
        in_w, out_w, xp_w, z_in, inw_bf, outw_bf, xpw_bf, z_bf);

    const u16* zcur = z_bf;
    for (int l = 0; l < 2; ++l) {
        fused_a_k<<<dim3(NCH, BATCH), 512, 0, stream>>>(
            zcur, inw_bf + (size_t)l*1024*256,
            conv_w + (size_t)l*DI*4, conv_b + (size_t)l*DI,
            (const __bf16*)(xpw_bf + (size_t)l*64*512),
            dt_w + (size_t)l*DI*16, dt_b + (size_t)l*DI,
            A_log + (size_t)l*DI*DS,
            xc_bf, dt_bf, gate_bf, BCg, Pbuf, Sbuf);
        scanB_k<<<16, 256, 0, stream>>>(Pbuf, Sbuf, Hbuf);
        fused_c_k<<<dim3(NCH, BATCH), 512, 0, stream>>>(
            xc_bf, dt_bf, BCg, Hbuf,
            A_log + (size_t)l*DI*DS, D_par + (size_t)l*DI,
            gate_bf, (const __bf16*)(outw_bf + (size_t)l*256*512),
            (l == 0) ? z2_bf : nullptr, (l == 1) ? outp : nullptr);
        zcur = z2_bf;
    }
}

// Round 8
// 261.076 us; speedup vs baseline: 1.0158x; 1.0158x over previous
//
#include <hip/hip_runtime.h>
#include <hip/hip_bf16.h>
#include <cstdint>
#include <cstddef>

#define DM   256
#define DI   512
#define DS   16
#define LSEQ 4096
#define BATCH 2
#define BLROWS (BATCH * LSEQ)   /* 8192 */
#define NCH  128                /* chunks per sequence */
#define CLEN 32                 /* steps per chunk */
#define XCP  520                /* padded LDS row stride (u16) */

/* fused_a LDS layout (bytes) */
#define OFF_INW 0               /* [kb 8][128][32] u16 = 65536 */
#define OFF_XC  0               /* overlay after in_proj: 32*520*2 = 33280 */
#define OFF_Z   65536           /* 48*264*2 = 25344 */
#define OFF_XD  65536           /* overlay: 32*68*4 = 8704 */
#define OFF_XX  90880           /* 35*520*2 = 36400 */
#define SMEM_SZ 127280

typedef __bf16 bf16x8 __attribute__((ext_vector_type(8)));
typedef float  f32x4  __attribute__((ext_vector_type(4)));
typedef unsigned short u16;
typedef u16 u16x8 __attribute__((ext_vector_type(8)));
typedef u16 u16x4 __attribute__((ext_vector_type(4)));

__device__ __forceinline__ u16 f2bfu(float f) {
    union { float f; unsigned u; } c; c.f = f;
    unsigned u = c.u;
    return (u16)((u + 0x7fffu + ((u >> 16) & 1u)) >> 16);
}
__device__ __forceinline__ float bfu2f(u16 u) {
    union { unsigned u; float f; } c; c.u = ((unsigned)u) << 16; return c.f;
}
__device__ __forceinline__ float siluf(float v) {
    return v * (1.0f / (1.0f + __expf(-v)));
}
__device__ __forceinline__ void gload_lds16(const void* g, void* l) {
    __builtin_amdgcn_global_load_lds(
        (const __attribute__((address_space(1))) unsigned int*)g,
        (__attribute__((address_space(3))) unsigned int*)l, 16, 0, 0);
}

/* ---------------- merged startup casts ---------------- */
#define N_INW  (2*1024*256)
#define N_OUTW (2*256*512)
#define N_XPW  (2*64*512)
#define N_Z    (BLROWS*DM)
__global__ __launch_bounds__(256) void cast_all_k(
    const float* __restrict__ in_w, const float* __restrict__ out_w,
    const float* __restrict__ xp_w, const float* __restrict__ z,
    u16* __restrict__ inw_bf, u16* __restrict__ outw_bf,
    u16* __restrict__ xpw_bf, u16* __restrict__ z_bf) {
    int i = blockIdx.x * 256 + threadIdx.x;
    if (i < N_INW) {
        inw_bf[i] = f2bfu(in_w[i]);
    } else if (i < N_INW + N_OUTW) {
        int j = i - N_INW;
        outw_bf[j] = f2bfu(out_w[j]);
    } else if (i < N_INW + N_OUTW + N_XPW) {
        int j = i - (N_INW + N_OUTW);
        int k = j & 511, o = (j >> 9) & 63, l = j >> 15;
        xpw_bf[j] = f2bfu((o < 48) ? xp_w[(l * 48 + o) * 512 + k] : 0.0f);
    } else {
        int j = i - (N_INW + N_OUTW + N_XPW);
        z_bf[j] = f2bfu(z[j]);
    }
}

/* ---------------- fused A: in_proj MFMA -> conv+silu -> x_proj -> dt -> scan -- */
/* grid (NCH, BATCH), 512 threads (8 waves). One block = one chunk, all 512 ch.  */
__global__ __launch_bounds__(512) void fused_a_k(
    const u16* __restrict__ zin, const u16* __restrict__ inw,
    const float* __restrict__ cw, const float* __restrict__ cb,
    const __bf16* __restrict__ xpw,
    const float* __restrict__ dtw, const float* __restrict__ dtb,
    const float* __restrict__ Alog,
    u16* __restrict__ xcb, u16* __restrict__ dtob, u16* __restrict__ gateb,
    float* __restrict__ BCg, u16* __restrict__ Pb, u16* __restrict__ Sb) {
    __shared__ __align__(16) char smem[SMEM_SZ];
    u16*  inw_s = (u16*)(smem + OFF_INW);
    u16*  z_s   = (u16*)(smem + OFF_Z);
    u16*  xx_s  = (u16*)(smem + OFF_XX);
    u16*  xc_s  = (u16*)(smem + OFF_XC);
    float* xd_s = (float*)(smem + OFF_XD);
    int tid = threadIdx.x;
    int c = blockIdx.x, b = blockIdx.y;
    int bl0 = b * LSEQ + c * CLEN;
    int wave = tid >> 6, lane = tid & 63;
    int row = lane & 15, q = lane >> 4;
    int d = tid;

    /* stage z slab: LDS rows 0..47 = t -3..44; rows>=35 zero; c==0 rows<3 zero */
    for (int idx = tid; idx < 48 * 32; idx += 512) {
        int r = idx >> 5, c8 = idx & 31;
        u16x8 v = {0,0,0,0,0,0,0,0};
        if (r < 35 && (c > 0 || r >= 3))
            v = *(const u16x8*)(zin + (size_t)(bl0 - 3 + r) * DM + c8 * 8);
        *(u16x8*)(z_s + r * 264 + c8 * 8) = v;
    }
    __syncthreads();

    /* A-fragments once into registers: af[mt][kb] (z_s never re-read) */
    bf16x8 af[3][8];
    #pragma unroll
    for (int mt = 0; mt < 3; ++mt)
        #pragma unroll
        for (int kb = 0; kb < 8; ++kb)
            af[mt][kb] = *(const bf16x8*)(z_s + (mt*16 + row) * 264 + kb*32 + q*8);

    /* in_proj: 8 col-groups of 128 rows of W; inw_s = [kb][128][32] u16 */
    for (int g = 0; g < 8; ++g) {
        /* stage 64 KB: wave w covers rows w*16..w*16+15 for each kb */
        #pragma unroll
        for (int kb = 0; kb < 8; ++kb)
            gload_lds16(inw + (size_t)(g*128 + wave*16 + (lane>>2)) * 256
                            + kb*32 + (lane&3)*8,
                        inw_s + kb*4096 + wave*16*32);
        __syncthreads();
        f32x4 acc[3] = {};
        #pragma unroll
        for (int kb = 0; kb < 8; ++kb) {
            bf16x8 bb = *(const bf16x8*)(inw_s + kb*4096 + (wave*16 + row)*32 + q*8);
            #pragma unroll
            for (int mt = 0; mt < 3; ++mt)
                acc[mt] = __builtin_amdgcn_mfma_f32_16x16x32_bf16(
                    af[mt][kb], bb, acc[mt], 0, 0, 0);
        }
        __syncthreads();
        /* write out: cols g*128 + wave*16 + row (C-layout: row = q*4+r) */
        int col = g * 128 + wave * 16 + row;
        #pragma unroll
        for (int mt = 0; mt < 3; ++mt)
            #pragma unroll
            for (int r = 0; r < 4; ++r) {
                int grow = mt * 16 + q * 4 + r;
                if (g < 4) {
                    if (grow < 35) xx_s[grow * XCP + col] = f2bfu(acc[mt][r]);
                } else {
                    int t = grow - 3;
                    if (t >= 0 && t < CLEN)
                        gateb[(size_t)(bl0 + t) * DI + (col - 512)] = f2bfu(acc[mt][r]);
                }
            }
    }
    __syncthreads();

    /* conv + silu: thread = channel; x(t') = xx_s[(t'+3)*XCP + d] */
    {
        float w0 = cw[d*4], w1 = cw[d*4+1], w2 = cw[d*4+2], w3 = cw[d*4+3];
        float bias = cb[d];
        float xm3 = bfu2f(xx_s[0*XCP + d]);
        float xm2 = bfu2f(xx_s[1*XCP + d]);
        float xm1 = bfu2f(xx_s[2*XCP + d]);
        #pragma unroll 4
        for (int t = 0; t < CLEN; ++t) {
            float xcur = bfu2f(xx_s[(t + 3) * XCP + d]);
            float v = siluf(fmaf(w0, xm3, fmaf(w1, xm2, fmaf(w2, xm1, fmaf(w3, xcur, bias)))));
            u16 vb = f2bfu(v);
            xc_s[t * XCP + d] = vb;                       /* overlays inw_s (dead) */
            xcb[(size_t)(bl0 + t) * DI + d] = vb;
            xm3 = xm2; xm2 = xm1; xm1 = xcur;
        }
    }
    __syncthreads();

    /* x_proj: xd[32,64] = xc_s[32,512] @ xpw[64,512]^T (8 waves: mt 2 x nt 4) */
    {
        int mt = wave & 1, nt = wave >> 1;
        f32x4 acc = {0.f, 0.f, 0.f, 0.f};
        #pragma unroll
        for (int kb = 0; kb < 16; ++kb) {
            bf16x8 a = *(const bf16x8*)&xc_s[(mt*16 + row) * XCP + kb*32 + q*8];
            bf16x8 bb = *(const bf16x8*)(xpw + (size_t)(nt*16 + row) * 512 + kb*32 + q*8);
            acc = __builtin_amdgcn_mfma_f32_16x16x32_bf16(a, bb, acc, 0, 0, 0);
        }
        #pragma unroll
        for (int r = 0; r < 4; ++r)
            xd_s[(mt*16 + q*4 + r) * 68 + nt*16 + row] = acc[r];   /* overlays z_s */
    }
    __syncthreads();

    /* store compact B,C (cols 16..47) for fused_c */
    for (int i = tid; i < CLEN * 32; i += 512) {
        int t = i >> 5, cc = i & 31;
        BCg[((size_t)(b*NCH + c) * CLEN + t) * 32 + cc] = xd_s[t*68 + 16 + cc];
    }

    /* dt = softplus(xd[:, :16] @ dtw^T + dtb); chunk scan -> P,S (bf16) */
    {
        float dtwr[16];
        const f32x4* w4 = (const f32x4*)(dtw + (size_t)d * 16);
        #pragma unroll
        for (int g = 0; g < 4; ++g) { f32x4 v = w4[g];
            dtwr[g*4] = v[0]; dtwr[g*4+1] = v[1]; dtwr[g*4+2] = v[2]; dtwr[g*4+3] = v[3]; }
        float dtbv = dtb[d];
        float Ac[16];
        const f32x4* a4 = (const f32x4*)(Alog + (size_t)d * 16);
        #pragma unroll
        for (int g = 0; g < 4; ++g) { f32x4 v = a4[g];
            #pragma unroll
            for (int j = 0; j < 4; ++j) Ac[g*4+j] = -__expf(v[j]); }
        bool fastp = true;
        #pragma unroll
        for (int n = 1; n < 16; ++n)
            fastp = fastp && (fabsf(Ac[n] - (float)(n+1) * Ac[0]) <= 1e-4f * fabsf(Ac[n]));
        float p[16], s[16];
        #pragma unroll
        for (int n = 0; n < 16; ++n) { p[n] = 1.0f; s[n] = 0.0f; }
        for (int t = 0; t < CLEN; ++t) {
            float acc = dtbv;
            #pragma unroll
            for (int r = 0; r < 16; ++r) acc = fmaf(xd_s[t*68 + r], dtwr[r], acc);
            float dtv = (acc > 20.0f) ? acc : logf(1.0f + __expf(acc));
            dtob[(size_t)(bl0 + t) * DI + d] = f2bfu(dtv);
            float xv = bfu2f(xc_s[t * XCP + d]);
            float dx = dtv * xv;
            float an[16];
            if (fastp) {
                float a0 = __expf(dtv * Ac[0]);
                an[0] = a0;
                #pragma unroll
                for (int n = 1; n < 16; ++n) an[n] = an[n-1] * a0;
            } else {
                #pragma unroll
                for (int n = 0; n < 16; ++n) an[n] = __expf(dtv * Ac[n]);
            }
            #pragma unroll
            for (int n = 0; n < 16; ++n) {
                s[n] = fmaf(an[n], s[n], xd_s[t*68 + 16 + n] * dx);
                p[n] *= an[n];
            }
        }
        size_t base = ((size_t)(b*NCH + c) * DI + d) * 16;
        u16x8 pv0, pv1, sv0, sv1;
        #pragma unroll
        for (int n = 0; n < 8; ++n) {
            pv0[n] = f2bfu(p[n]);   pv1[n] = f2bfu(p[8+n]);
            sv0[n] = f2bfu(s[n]);   sv1[n] = f2bfu(s[8+n]);
        }
        *(u16x8*)(Pb + base)     = pv0;  *(u16x8*)(Pb + base + 8) = pv1;
        *(u16x8*)(Sb + base)     = sv0;  *(u16x8*)(Sb + base + 8) = sv1;
    }
}

/* ---------------- scanB: stitch chunk entry states (bf16 P,S -> f32 H) -------- */
__global__ __launch_bounds__(256) void scanB_k(
    const u16* __restrict__ Pb, const u16* __restrict__ Sb,
    float* __restrict__ H) {
    int i = blockIdx.x * 256 + threadIdx.x;   /* BATCH*DI*DS/4 = 4096 */
    int b = i >> 11, j4 = i & 2047;
    f32x4 h = {0.f, 0.f, 0.f, 0.f};
    for (int c = 0; c < NCH; ++c) {
        size_t i4 = (size_t)(b*NCH + c) * 2048 + j4;
        u16x4 pv = ((const u16x4*)Pb)[i4];
        u16x4 sv = ((const u16x4*)Sb)[i4];
        ((f32x4*)H)[i4] = h;
        #pragma unroll
        for (int j = 0; j < 4; ++j) h[j] = fmaf(bfu2f(pv[j]), h[j], bfu2f(sv[j]));
    }
}

/* ---------------- fused C: scan replay -> y slab (LDS) -> out_proj MFMA ------- */
__global__ __launch_bounds__(512) void fused_c_k(
    const u16* __restrict__ xcb, const u16* __restrict__ dtob,
    const float* __restrict__ BCg, const float* __restrict__ H,
    const float* __restrict__ Alog, const float* __restrict__ Dp,
    const u16* __restrict__ gateb, const __bf16* __restrict__ outw,
    u16* __restrict__ Ob, float* __restrict__ Of) {
    __shared__ u16 y_s[CLEN * XCP];        /* 33.3 KB */
    __shared__ float BCs[CLEN * 32];       /* 4 KB */
    int tid = threadIdx.x;
    int c = blockIdx.x, b = blockIdx.y;
    int bl0 = b * LSEQ + c * CLEN;
    int d = tid;

    for (int i = tid; i < CLEN * 32; i += 512)
        BCs[i] = BCg[(size_t)(b*NCH + c) * (CLEN*32) + i];

    float Ac[16], h[16];
    {
        const f32x4* a4 = (const f32x4*)(Alog + (size_t)d * 16);
        const f32x4* h4 = (const f32x4*)(H + ((size_t)(b*NCH + c) * DI + d) * 16);
        #pragma unroll
        for (int g = 0; g < 4; ++g) {
            f32x4 av = a4[g]; f32x4 hv = h4[g];
            #pragma unroll
            for (int j = 0; j < 4; ++j) { Ac[g*4+j] = -__expf(av[j]); h[g*4+j] = hv[j]; }
        }
    }
    bool fastp = true;
    #pragma unroll
    for (int n = 1; n < 16; ++n)
        fastp = fastp && (fabsf(Ac[n] - (float)(n+1) * Ac[0]) <= 1e-4f * fabsf(Ac[n]));
    float Dv = Dp[d];
    __syncthreads();

    #pragma unroll 4
    for (int t = 0; t < CLEN; ++t) {
        float dtv = bfu2f(dtob[(size_t)(bl0 + t) * DI + d]);
        float xv  = bfu2f(xcb[(size_t)(bl0 + t) * DI + d]);
        float gv  = bfu2f(gateb[(size_t)(bl0 + t) * DI + d]);
        float dx = dtv * xv;
        float an[16];
        if (fastp) {
            float a0 = __expf(dtv * Ac[0]);
            an[0] = a0;
            #pragma unroll
            for (int n = 1; n < 16; ++n) an[n] = an[n-1] * a0;
        } else {
            #pragma unroll
            for (int n = 0; n < 16; ++n) an[n] = __expf(dtv * Ac[n]);
        }
        float y = 0.f;
        #pragma unroll
        for (int n = 0; n < 16; ++n) {
            h[n] = fmaf(an[n], h[n], BCs[t*32 + n] * dx);
            y = fmaf(h[n], BCs[t*32 + 16 + n], y);
        }
        float yv = fmaf(xv, Dv, y) * siluf(gv);
        y_s[t * XCP + d] = f2bfu(yv);
    }
    __syncthreads();

    /* out_proj: O[32,256] = y_s[32,512] @ outw[256,512]^T; 8 waves: mt 2 x ng 4 */
    {
        int wave = tid >> 6, lane = tid & 63;
        int row = lane & 15, q = lane >> 4;
        int mt = wave & 1, ng = wave >> 1;
        f32x4 acc[4] = {};
        #pragma unroll
        for (int kb = 0; kb < 16; ++kb) {
            bf16x8 a = *(const bf16x8*)&y_s[(mt*16 + row) * XCP + kb*32 + q*8];
            #pragma unroll
            for (int ni = 0; ni < 4; ++ni) {
                bf16x8 bb = *(const bf16x8*)(outw +
                    (size_t)(ng*64 + ni*16 + row) * 512 + kb*32 + q*8);
                acc[ni] = __builtin_amdgcn_mfma_f32_16x16x32_bf16(a, bb, acc[ni], 0, 0, 0);
            }
        }
        #pragma unroll
        for (int r = 0; r < 4; ++r) {
            size_t gr = (size_t)(bl0 + mt*16 + q*4 + r) * DM;
            #pragma unroll
            for (int ni = 0; ni < 4; ++ni) {
                int gc = ng*64 + ni*16 + row;
                if (Ob) Ob[gr + gc] = f2bfu(acc[ni][r]);
                else    Of[gr + gc] = acc[ni][r];
            }
        }
    }
}

/* ================================================================== */
extern "C" void kernel_launch(void* const* d_in, const int* in_sizes, int n_in,
                              void* d_out, int out_size, void* d_ws, size_t ws_size,
                              hipStream_t stream) {
    (void)in_sizes; (void)n_in; (void)out_size; (void)ws_size;
    const float* z_in   = (const float*)d_in[0];
    const float* in_w   = (const float*)d_in[1];
    const float* conv_w = (const float*)d_in[2];
    const float* conv_b = (const float*)d_in[3];
    const float* xp_w   = (const float*)d_in[4];
    const float* dt_w   = (const float*)d_in[5];
    const float* dt_b   = (const float*)d_in[6];
    const float* A_log  = (const float*)d_in[7];
    const float* D_par  = (const float*)d_in[8];
    const float* out_w  = (const float*)d_in[9];
    float* outp = (float*)d_out;

    char* p = (char*)d_ws;
    auto alloc = [&](size_t bytes) { char* r = p; p += (bytes + 255) & ~(size_t)255; return r; };
    u16* z_bf    = (u16*)alloc((size_t)BLROWS*DM*2);
    u16* z2_bf   = (u16*)alloc((size_t)BLROWS*DM*2);
    u16* xc_bf   = (u16*)alloc((size_t)BLROWS*DI*2);
    u16* dt_bf   = (u16*)alloc((size_t)BLROWS*DI*2);
    u16* gate_bf = (u16*)alloc((size_t)BLROWS*DI*2);
    u16* inw_bf  = (u16*)alloc((size_t)2*1024*256*2);
    u16* outw_bf = (u16*)alloc((size_t)2*256*512*2);
    u16* xpw_bf  = (u16*)alloc((size_t)2*64*512*2);
    float* BCg   = (float*)alloc((size_t)BATCH*NCH*CLEN*32*4);
    u16* Pbuf    = (u16*)alloc((size_t)BATCH*NCH*DI*DS*2);
    u16* Sbuf    = (u16*)alloc((size_t)BATCH*NCH*DI*DS*2);
    float* Hbuf  = (float*)alloc((size_t)BATCH*NCH*DI*DS*4);

    cast_all_k<<<(N_INW + N_OUTW + N_XPW + N_Z)/256, 256, 0, stream>>>(
        in_w, out_w, xp_w, z_in, inw_bf, outw_bf, xpw_bf, z_bf);

    const u16* zcur = z_bf;
    for (int l = 0; l < 2; ++l) {
        fused_a_k<<<dim3(NCH, BATCH), 512, 0, stream>>>(
            zcur, inw_bf + (size_t)l*1024*256,
            conv_w + (size_t)l*DI*4, conv_b + (size_t)l*DI,
            (const __bf16*)(xpw_bf + (size_t)l*64*512),
            dt_w + (size_t)l*DI*16, dt_b + (size_t)l*DI,
            A_log + (size_t)l*DI*DS,
            xc_bf, dt_bf, gate_bf, BCg, Pbuf, Sbuf);
        scanB_k<<<16, 256, 0, stream>>>(Pbuf, Sbuf, Hbuf);
        fused_c_k<<<dim3(NCH, BATCH), 512, 0, stream>>>(
            xc_bf, dt_bf, BCg, Hbuf,
            A_log + (size_t)l*DI*DS, D_par + (size_t)l*DI,
            gate_bf, (const __bf16*)(outw_bf + (size_t)l*256*512),
            (l == 0) ? z2_bf : nullptr, (l == 1) ? outp : nullptr);
        zcur = z2_bf;
    }
}